// Round 5
// baseline (316.262 us; speedup 1.0000x reference)
//
#include <hip/hip_runtime.h>

#define NB 64
#define NC 768
#define NN 576          // 24*24
#define NF4 144         // NN/4

#define HR 16           // heat rows per chunk
#define HCH 48          // 768/16 -> 3072 heat blocks per input
#define GR 12           // gsum rows per chunk (192 threads = 3 waves * 4 rows)
#define GCH 64          // 768/12 -> 4096 gsum blocks per input

// ---- workspace layout (bytes) ----
#define OFF_HM   0ull                          // double [2][NB][HCH][NN] = 28.3 MB
#define SZ_HM    (2ull*NB*HCH*NN*8ull)
#define OFF_GID  (OFF_HM + SZ_HM)              // uchar  [2][NB][NN]
#define SZ_GID   (2ull*NB*NN)
#define OFF_GP   (OFF_GID + SZ_GID)            // float  [2][NB][NC][3][4]
#define SZ_GP    (2ull*NB*NC*12ull*4ull)
#define OFF_PB   (OFF_GP + SZ_GP)              // double [NB]

// ---- heat body: 192 threads, 16-row chunk, f64 accumulate, 24 loads in flight ----
__device__ __forceinline__ void heat_body(const float* __restrict__ f,
                                          double* __restrict__ hm,
                                          int b, int chunk, int t) {
    const float* p = f + (size_t)b * NC * NN + (size_t)chunk * HR * NN;
    double d0 = 0, d1 = 0, d2 = 0;
    #pragma unroll
    for (int r0 = 0; r0 < HR; r0 += 8) {
        float v[24];
        #pragma unroll
        for (int rr = 0; rr < 8; ++rr) {
            const float* row = p + (size_t)(r0 + rr) * NN + t;
            v[rr * 3 + 0] = row[0];
            v[rr * 3 + 1] = row[192];
            v[rr * 3 + 2] = row[384];
        }
        #pragma unroll
        for (int rr = 0; rr < 8; ++rr) {
            d0 += (double)v[rr * 3 + 0];
            d1 += (double)v[rr * 3 + 1];
            d2 += (double)v[rr * 3 + 2];
        }
    }
    double* o = hm + ((size_t)b * HCH + chunk) * NN;
    o[t] = d0; o[t + 192] = d1; o[t + 384] = d2;
}

// ---- gsum body: 192 threads, 12-row chunk; 16 lanes per c-row, packed-gid
//      select, 2 shfl_xor -> 4 partials per (c,g) ----
__device__ __forceinline__ void gsum_body(const float* __restrict__ f,
                                          const unsigned* __restrict__ gw,
                                          float* __restrict__ gp,
                                          int b, int chunk, int t) {
    const float4* plane = (const float4*)(f + (size_t)b * NC * NN);
    int w = t >> 6, l = t & 63;
    int sub = l & 15, rr = l >> 4;

    unsigned g[9];
    const unsigned* gwb = gw + (size_t)b * NF4;
    #pragma unroll
    for (int k = 0; k < 9; ++k) g[k] = gwb[sub + 16 * k];

    int c = chunk * GR + w * 4 + rr;
    const float4* row = plane + (size_t)c * NF4 + sub;
    float4 v[9];
    #pragma unroll
    for (int k = 0; k < 9; ++k) v[k] = row[16 * k];
    float sa = 0.f, s1 = 0.f, s2 = 0.f;
    #pragma unroll
    for (int k = 0; k < 9; ++k) {
        unsigned gwk = g[k];
        float x; unsigned gg;
        x = v[k].x; gg = gwk & 0xffu;         sa += x; s1 += (gg >= 1u) ? x : 0.f; s2 += (gg == 2u) ? x : 0.f;
        x = v[k].y; gg = (gwk >> 8) & 0xffu;  sa += x; s1 += (gg >= 1u) ? x : 0.f; s2 += (gg == 2u) ? x : 0.f;
        x = v[k].z; gg = (gwk >> 16) & 0xffu; sa += x; s1 += (gg >= 1u) ? x : 0.f; s2 += (gg == 2u) ? x : 0.f;
        x = v[k].w; gg = gwk >> 24;           sa += x; s1 += (gg >= 1u) ? x : 0.f; s2 += (gg == 2u) ? x : 0.f;
    }
    sa += __shfl_xor(sa, 4); s1 += __shfl_xor(s1, 4); s2 += __shfl_xor(s2, 4);
    sa += __shfl_xor(sa, 8); s1 += __shfl_xor(s1, 8); s2 += __shfl_xor(s2, 8);
    if (sub < 4) {
        float* o = gp + (size_t)b * NC * 12 + (size_t)c * 12;
        o[0 * 4 + sub] = sa - s1;      // group 0
        o[1 * 4 + sub] = s1 - s2;      // group 1
        o[2 * 4 + sub] = s2;           // group 2
    }
}

// K: heat only (one input). grid = NB*HCH = 3072.
__global__ __launch_bounds__(192, 8) void k_heat(const float* __restrict__ f,
                                                 double* __restrict__ hm) {
    int bx = blockIdx.x;
    int b = bx / HCH, chunk = bx - b * HCH;
    heat_body(f, hm, b, chunk, threadIdx.x);
}

// K: mixed roles — gsum(fA, L3-hot) overlapped with heat(fB, HBM).
// grid = 7168 = 1024 groups * (4 gsum + 3 heat).
__global__ __launch_bounds__(192, 4) void k_mix(const float* __restrict__ fB,
                                                double* __restrict__ hmB,
                                                const float* __restrict__ fA,
                                                const unsigned* __restrict__ gwA,
                                                float* __restrict__ gpA) {
    int bx = blockIdx.x, t = threadIdx.x;
    int grp = bx / 7, r = bx - grp * 7;
    if (r < 4) {
        int gb = grp * 4 + r;          // 0..4095
        gsum_body(fA, gwA, gpA, gb >> 6, gb & 63, t);
    } else {
        int hb = grp * 3 + (r - 4);    // 0..3071
        heat_body(fB, hmB, hb / HCH, hb % HCH, t);
    }
}

// K: gsum only (one input). grid = NB*GCH = 4096.
__global__ __launch_bounds__(192, 4) void k_gsum(const float* __restrict__ f,
                                                 const unsigned* __restrict__ gw,
                                                 float* __restrict__ gp) {
    int bx = blockIdx.x;
    gsum_body(f, gw, gp, bx >> 6, bx & 63, threadIdx.x);
}

// K: combine 48 f64 partials, rank (stable desc), emit gid byte. grid = NB.
__global__ __launch_bounds__(576) void k_rank(const double* __restrict__ hm,
                                              unsigned char* __restrict__ gid8) {
    int b = blockIdx.x;
    int t = threadIdx.x;
    const double* p = hm + (size_t)b * HCH * NN + t;
    double h = 0;
    #pragma unroll
    for (int c0 = 0; c0 < HCH; c0 += 16) {
        double v[16];
        #pragma unroll
        for (int ch = 0; ch < 16; ++ch) v[ch] = p[(size_t)(c0 + ch) * NN];
        #pragma unroll
        for (int ch = 0; ch < 16; ++ch) h += v[ch];
    }
    __shared__ double hs[NN];
    hs[t] = h;
    __syncthreads();
    int cnt = 0;
    for (int j = 0; j < NN; ++j) {     // uniform j => LDS broadcast
        double hj = hs[j];
        cnt += (hj > h) ? 1 : ((hj == h && j < t) ? 1 : 0);
    }
    gid8[(size_t)b * NN + t] = (cnt >= 384) ? 2 : ((cnt >= 192) ? 1 : 0);
}

// K: per-b finish: sum 4 partials, /192, L2-norm (f64), MSE partial.
__global__ __launch_bounds__(256) void k_mse(const float* __restrict__ gp,
                                             double* __restrict__ pb) {
    int b = blockIdx.x;
    int t = threadIdx.x;
    int w = t >> 6, l = t & 63;
    const float4* s1 = (const float4*)(gp + (size_t)b * NC * 12);
    const float4* s2 = (const float4*)(gp + (size_t)(NB + b) * NC * 12);

    double v1[9], v2[9];
    double q1 = 0, q2 = 0;
    #pragma unroll
    for (int k = 0; k < 9; ++k) {       // 2304 entries = 256*9; entry e = c*3+g
        int e = t + 256 * k;
        float4 a = s1[e], c4 = s2[e];
        v1[k] = ((double)a.x + (double)a.y + (double)a.z + (double)a.w) * (1.0 / 192.0);
        v2[k] = ((double)c4.x + (double)c4.y + (double)c4.z + (double)c4.w) * (1.0 / 192.0);
        q1 += v1[k] * v1[k];
        q2 += v2[k] * v2[k];
    }
    #pragma unroll
    for (int m = 32; m; m >>= 1) { q1 += __shfl_xor(q1, m); q2 += __shfl_xor(q2, m); }
    __shared__ double red1[4], red2[4];
    if (l == 0) { red1[w] = q1; red2[w] = q2; }
    __syncthreads();
    q1 = red1[0] + red1[1] + red1[2] + red1[3];
    q2 = red2[0] + red2[1] + red2[2] + red2[3];
    double inv1 = 1.0 / fmax(sqrt(q1), 1e-12);
    double inv2 = 1.0 / fmax(sqrt(q2), 1e-12);

    double acc = 0;
    #pragma unroll
    for (int k = 0; k < 9; ++k) {
        double d = v1[k] * inv1 - v2[k] * inv2;
        acc += d * d;
    }
    #pragma unroll
    for (int m = 32; m; m >>= 1) acc += __shfl_xor(acc, m);
    __syncthreads();
    if (l == 0) red1[w] = acc;
    __syncthreads();
    if (t == 0) pb[b] = red1[0] + red1[1] + red1[2] + red1[3];
}

// K: final scalar.
__global__ __launch_bounds__(64) void k_final(const double* __restrict__ pb,
                                              float* __restrict__ out) {
    int l = threadIdx.x;
    double v = pb[l];
    #pragma unroll
    for (int m = 32; m; m >>= 1) v += __shfl_xor(v, m);
    if (l == 0) out[0] = (float)(v / ((double)NB * 3.0 * (double)NC));
}

extern "C" void kernel_launch(void* const* d_in, const int* in_sizes, int n_in,
                              void* d_out, int out_size, void* d_ws, size_t ws_size,
                              hipStream_t stream) {
    (void)in_sizes; (void)n_in; (void)out_size; (void)ws_size;
    const float* f1 = (const float*)d_in[0];
    const float* f2 = (const float*)d_in[1];
    float* out = (float*)d_out;
    char* ws = (char*)d_ws;

    double*        hm1  = (double*)(ws + OFF_HM);                 // input 1
    double*        hm2  = hm1 + (size_t)NB * HCH * NN;            // input 2
    unsigned char* gid1 = (unsigned char*)(ws + OFF_GID);
    unsigned char* gid2 = gid1 + (size_t)NB * NN;
    float*         gp1  = (float*)(ws + OFF_GP);
    float*         gp2  = gp1 + (size_t)NB * NC * 12;
    double*        pb   = (double*)(ws + OFF_PB);

    // Phase f2 first (MRU in L3 from the harness restore), then overlap
    // gsum(f2) [L3-hot] with heat(f1) [HBM] in one mixed launch.
    k_heat <<<NB * HCH, 192, 0, stream>>>(f2, hm2);
    k_rank <<<NB,       576, 0, stream>>>(hm2, gid2);
    k_mix  <<<7 * 1024, 192, 0, stream>>>(f1, hm1, f2, (const unsigned*)gid2, gp2);
    k_rank <<<NB,       576, 0, stream>>>(hm1, gid1);
    k_gsum <<<NB * GCH, 192, 0, stream>>>(f1, (const unsigned*)gid1, gp1);
    k_mse  <<<NB,       256, 0, stream>>>(gp1, pb);
    k_final<<<1,        64,  0, stream>>>(pb, out);
}